// Round 6
// baseline (48.200 us; speedup 1.0000x reference)
//
#include <hip/hip_runtime.h>
#include <hip/hip_bf16.h>

typedef __bf16 bf16x8 __attribute__((ext_vector_type(8)));
typedef float  f32x4  __attribute__((ext_vector_type(4)));

#define NROWS 8192
#define DIM   128
#define NB2   32            // 8192 / 256 row-blocks
#define JOBS2 528           // 32*33/2 upper-tri incl diag (per matrix)

__device__ __forceinline__ float waveReduceSum(float v) {
    for (int off = 32; off; off >>= 1) v += __shfl_xor(v, off, 64);
    return v;
}

__device__ __forceinline__ float fast_exp2(float x) {
    return __builtin_amdgcn_exp2f(x);
}

// async global->LDS, 16B per lane; lds dest is wave-uniform base (+lane*16 by HW)
__device__ __forceinline__ void gload16(const void* g, void* l) {
    __builtin_amdgcn_global_load_lds(
        (const __attribute__((address_space(1))) unsigned int*)(uintptr_t)g,
        (__attribute__((address_space(3))) unsigned int*)(uintptr_t)l,
        16, 0, 0);
}

__device__ __forceinline__ int tri2(int b) { return b * NB2 - (b * (b - 1)) / 2; }

// ---------------------------------------------------------------------------
// Kernel 1: normalize rows (float4, 2 rows/wave), align partials, bf16 copies.
// 1024 blocks x 256 threads.
// ---------------------------------------------------------------------------
__global__ __launch_bounds__(256) void prep_kernel(
    const float* __restrict__ users, const float* __restrict__ pos,
    __bf16* __restrict__ Uh, __bf16* __restrict__ Ph,
    double* __restrict__ alignPart)
{
    const int tid  = threadIdx.x;
    const int lane = tid & 63;
    const int w    = tid >> 6;
    const int l32  = lane & 31;
    const int half = lane >> 5;
    const int r    = blockIdx.x * 8 + w * 2 + half;

    const float4 u4 = ((const float4*)users)[r * 32 + l32];
    const float4 p4 = ((const float4*)pos )[r * 32 + l32];

    float su = u4.x*u4.x + u4.y*u4.y + u4.z*u4.z + u4.w*u4.w;
    float sp = p4.x*p4.x + p4.y*p4.y + p4.z*p4.z + p4.w*p4.w;
    for (int off = 16; off; off >>= 1) {      // half-wave reduce (per row)
        su += __shfl_xor(su, off, 64);
        sp += __shfl_xor(sp, off, 64);
    }
    const float nu  = fmaxf(sqrtf(su), 1e-12f);
    const float npp = fmaxf(sqrtf(sp), 1e-12f);

    const float ux = u4.x / nu,  uy = u4.y / nu,  uz = u4.z / nu,  uw = u4.w / nu;
    const float px = p4.x / npp, py = p4.y / npp, pz = p4.z / npp, pw = p4.w / npp;

    union { __bf16 h[4]; uint2 q; } cu, cp;
    cu.h[0] = (__bf16)ux; cu.h[1] = (__bf16)uy; cu.h[2] = (__bf16)uz; cu.h[3] = (__bf16)uw;
    cp.h[0] = (__bf16)px; cp.h[1] = (__bf16)py; cp.h[2] = (__bf16)pz; cp.h[3] = (__bf16)pw;
    ((uint2*)Uh)[r * 32 + l32] = cu.q;
    ((uint2*)Ph)[r * 32 + l32] = cp.q;

    const float dx = ux - px, dy = uy - py, dz = uz - pz, dw = uw - pw;
    float al = dx*dx + dy*dy + dz*dz + dw*dw;
    for (int off = 16; off; off >>= 1) al += __shfl_xor(al, off, 64);
    al += __shfl_xor(al, 32, 64);             // combine the two rows

    __shared__ float wsum[4];
    if (lane == 0) wsum[w] = al;
    __syncthreads();
    if (tid == 0)
        alignPart[blockIdx.x] = (double)wsum[0] + (double)wsum[1]
                              + (double)wsum[2] + (double)wsum[3];
}

// ---------------------------------------------------------------------------
// Kernel 2: 256x256 tile of G = Xn*Xn^T per block (bi<=bj tiles; off-diag x2).
//   512 threads = 8 waves as 2x4; wave tile 128x64 (acc[8][4] 16x16 frags).
//   LDS 64KB: A-half [256][64]bf16 at 0, B-half at 32768. K processed in two
//   halves reusing the same buffer (3 barriers). Rows = 128B = 8 chunks of
//   16B; LDS(r,c) holds global chunk c^(r&7) (pre-swizzled source, linear
//   gload_lds dest; reads XOR back). 2 blocks/CU co-resident hide stalls.
// ---------------------------------------------------------------------------
__global__ __launch_bounds__(512) void gram_kernel(
    const __bf16* __restrict__ Uh, const __bf16* __restrict__ Ph,
    double* __restrict__ Spart)
{
    __shared__ __align__(16) unsigned char smem[65536];
    __shared__ float wsum[8];

    const int bid = blockIdx.x;
    const int mat = bid >= JOBS2;
    const int t   = bid - (mat ? JOBS2 : 0);

    int bi = (int)((NB2 + 0.5f) - sqrtf((NB2 + 0.5f) * (NB2 + 0.5f) - 2.0f * (float)t));
    if (bi > 0 && tri2(bi) > t) --bi;
    if (tri2(bi + 1) <= t) ++bi;
    const int bj = bi + (t - tri2(bi));

    const char* __restrict__ Xb = (const char*)(mat ? Ph : Uh);

    const int tid  = threadIdx.x;
    const int lane = tid & 63;
    const int w    = tid >> 6;

    // ---- staging geometry: thread covers rows r0+64i, chunk (tid&7) ----
    const int r0 = tid >> 3;                        // 0..63
    const int gcOff = (((tid & 7) ^ (r0 & 7)) << 4);
    const char* gA0 = Xb + (size_t)(bi * 256 + r0) * 256 + gcOff;
    const char* gB0 = Xb + (size_t)(bj * 256 + r0) * 256 + gcOff;
    unsigned char* lA0 = smem + w * 1024;           // wave-uniform base (A)
    unsigned char* lB0 = lA0 + 32768;               // (B)

#define STAGE(h)                                                           \
    {                                                                      \
        const int hb = (h) * 128;                                          \
        _Pragma("unroll")                                                  \
        for (int i_ = 0; i_ < 4; ++i_) {                                   \
            gload16(gA0 + hb + i_ * 16384, lA0 + i_ * 8192);               \
            gload16(gB0 + hb + i_ * 16384, lB0 + i_ * 8192);               \
        }                                                                  \
    }

    // ---- fragment read geometry (2x4 waves; wave tile 128 rows x 64 cols) --
    const int wm = w >> 2, wn = w & 3;
    const int lr = lane & 15;
    const int lg = lane >> 4;
    const unsigned cxor = (unsigned)(lr & 7);
    const unsigned aOff = (unsigned)(wm * 128 + lr) * 128;
    const unsigned bOff = (unsigned)(wn * 64 + lr) * 128 + 32768;

    f32x4 acc[8][4];
#pragma unroll
    for (int mi = 0; mi < 8; ++mi)
#pragma unroll
        for (int ni = 0; ni < 4; ++ni)
            acc[mi][ni] = (f32x4){0.f, 0.f, 0.f, 0.f};

#define COMPUTE                                                             \
    {                                                                       \
        _Pragma("unroll")                                                   \
        for (int ks2 = 0; ks2 < 2; ++ks2) {                                 \
            const unsigned sc = (((unsigned)(ks2 * 4 + lg)) ^ cxor) << 4;   \
            bf16x8 b[4];                                                    \
            _Pragma("unroll")                                               \
            for (int ni = 0; ni < 4; ++ni)                                  \
                b[ni] = *reinterpret_cast<const bf16x8*>(                   \
                    smem + bOff + ni * 2048 + sc);                          \
            _Pragma("unroll")                                               \
            for (int mi = 0; mi < 8; ++mi) {                                \
                const bf16x8 a = *reinterpret_cast<const bf16x8*>(          \
                    smem + aOff + mi * 2048 + sc);                          \
                _Pragma("unroll")                                           \
                for (int ni = 0; ni < 4; ++ni)                              \
                    acc[mi][ni] = __builtin_amdgcn_mfma_f32_16x16x32_bf16(  \
                        a, b[ni], acc[mi][ni], 0, 0, 0);                    \
            }                                                               \
        }                                                                   \
    }

    STAGE(0)
    __syncthreads();        // h0 staged
    COMPUTE
    __syncthreads();        // h0 reads done; buffer reusable
    STAGE(1)
    __syncthreads();        // h1 staged
    COMPUTE

    // ---- epilogue: sum exp2(C1*dot - C1) == exp(-2*d^2) ----
    const float C1 = 4.0f * 1.4426950408889634f;   // 4*log2(e)
    float s0 = 0.f, s1 = 0.f, s2 = 0.f, s3 = 0.f;
#pragma unroll
    for (int mi = 0; mi < 8; ++mi)
#pragma unroll
        for (int ni = 0; ni < 4; ++ni) {
            const f32x4 v = acc[mi][ni];
            s0 += fast_exp2(v[0] * C1 - C1);
            s1 += fast_exp2(v[1] * C1 - C1);
            s2 += fast_exp2(v[2] * C1 - C1);
            s3 += fast_exp2(v[3] * C1 - C1);
        }

    const float s = waveReduceSum((s0 + s1) + (s2 + s3));
    if (lane == 0) wsum[w] = s;
    __syncthreads();
    if (tid == 0) {
        double bs = 0.0;
        for (int i = 0; i < 8; ++i) bs += (double)wsum[i];
        if (bi != bj) bs *= 2.0;     // off-diagonal tile counts twice in S_full
        Spart[bid] = bs;
    }
#undef STAGE
#undef COMPUTE
}

// ---------------------------------------------------------------------------
// Kernel 3: final reduction + loss formula. One block, 1024 threads.
// ---------------------------------------------------------------------------
__global__ __launch_bounds__(1024) void finalize_kernel(
    const double* __restrict__ alignPart, const double* __restrict__ Spart,
    float* __restrict__ out)
{
    const int tid = threadIdx.x;
    double a = 0.0, su = 0.0, sp = 0.0;
    for (int i = tid; i < 1024; i += 1024) a += alignPart[i];
    for (int i = tid; i < 2 * JOBS2; i += 1024) {
        const double v = Spart[i];
        if (i < JOBS2) su += v; else sp += v;
    }
    for (int off = 32; off; off >>= 1) {
        a  += __shfl_xor(a,  off, 64);
        su += __shfl_xor(su, off, 64);
        sp += __shfl_xor(sp, off, 64);
    }
    __shared__ double sh[3][16];
    const int lane = tid & 63, wid = tid >> 6;
    if (lane == 0) { sh[0][wid] = a; sh[1][wid] = su; sh[2][wid] = sp; }
    __syncthreads();
    if (tid == 0) {
        double A = 0.0, SU = 0.0, SP = 0.0;
        for (int i = 0; i < 16; ++i) { A += sh[0][i]; SU += sh[1][i]; SP += sh[2][i]; }
        const double Nd = 8192.0;
        const double npairs = Nd * (Nd - 1.0) * 0.5;
        const double align = A / Nd;
        const double mu = (SU - Nd) * 0.5 / npairs;
        const double mp = (SP - Nd) * 0.5 / npairs;
        const double uniform = 0.25 * (log(mu) + log(mp));
        out[0] = (float)((align + uniform) / 8192.0);
    }
}

// ---------------------------------------------------------------------------
extern "C" void kernel_launch(void* const* d_in, const int* in_sizes, int n_in,
                              void* d_out, int out_size, void* d_ws, size_t ws_size,
                              hipStream_t stream)
{
    const float* users = (const float*)d_in[0];
    const float* pos   = (const float*)d_in[1];
    // d_in[2] (neg_items) intentionally unused, matching the reference.
    float* out = (float*)d_out;

    char* ws = (char*)d_ws;
    __bf16* Uh = (__bf16*)ws;                              // 2 MiB
    __bf16* Ph = (__bf16*)(ws + 2097152);                  // 2 MiB
    double* alignPart = (double*)(ws + 4194304);           // 1024 doubles
    double* Spart     = (double*)(ws + 4194304 + 8192);    // 1056 doubles

    hipLaunchKernelGGL(prep_kernel, dim3(1024), dim3(256), 0, stream,
                       users, pos, Uh, Ph, alignPart);
    hipLaunchKernelGGL(gram_kernel, dim3(2 * JOBS2), dim3(512), 0, stream,
                       Uh, Ph, Spart);
    hipLaunchKernelGGL(finalize_kernel, dim3(1), dim3(1024), 0, stream,
                       alignPart, Spart, out);
}

// Round 7
// 38.382 us; speedup vs baseline: 1.2558x; 1.2558x over previous
//
#include <hip/hip_runtime.h>
#include <hip/hip_bf16.h>

typedef __bf16 bf16x8 __attribute__((ext_vector_type(8)));
typedef float  f32x4  __attribute__((ext_vector_type(4)));

#define NROWS 8192
#define DIM   128
#define NB    64            // 8192 / 128 row-blocks
#define JOBS_PER_MAT 2080   // 64*65/2 upper-tri incl diag

__device__ __forceinline__ float waveReduceSum(float v) {
    for (int off = 32; off; off >>= 1) v += __shfl_xor(v, off, 64);
    return v;
}

__device__ __forceinline__ float fast_exp2(float x) {
    return __builtin_amdgcn_exp2f(x);
}

// async global->LDS, 16B per lane; lds dest is wave-uniform base (+lane*16 by HW)
__device__ __forceinline__ void gload16(const void* g, void* l) {
    __builtin_amdgcn_global_load_lds(
        (const __attribute__((address_space(1))) unsigned int*)(uintptr_t)g,
        (__attribute__((address_space(3))) unsigned int*)(uintptr_t)l,
        16, 0, 0);
}

__device__ __forceinline__ int tri(int b) { return b * NB - (b * (b - 1)) / 2; }

// ---------------------------------------------------------------------------
// Kernel 1: normalize rows (float4, 2 rows/wave), align partials, bf16 copies.
// ---------------------------------------------------------------------------
__global__ __launch_bounds__(256) void prep_kernel(
    const float* __restrict__ users, const float* __restrict__ pos,
    __bf16* __restrict__ Uh, __bf16* __restrict__ Ph,
    double* __restrict__ alignPart)
{
    const int tid  = threadIdx.x;
    const int lane = tid & 63;
    const int w    = tid >> 6;
    const int l32  = lane & 31;
    const int half = lane >> 5;
    const int r    = blockIdx.x * 8 + w * 2 + half;

    const float4 u4 = ((const float4*)users)[r * 32 + l32];
    const float4 p4 = ((const float4*)pos )[r * 32 + l32];

    float su = u4.x*u4.x + u4.y*u4.y + u4.z*u4.z + u4.w*u4.w;
    float sp = p4.x*p4.x + p4.y*p4.y + p4.z*p4.z + p4.w*p4.w;
    for (int off = 16; off; off >>= 1) {
        su += __shfl_xor(su, off, 64);
        sp += __shfl_xor(sp, off, 64);
    }
    const float nu  = fmaxf(sqrtf(su), 1e-12f);
    const float npp = fmaxf(sqrtf(sp), 1e-12f);

    const float ux = u4.x / nu,  uy = u4.y / nu,  uz = u4.z / nu,  uw = u4.w / nu;
    const float px = p4.x / npp, py = p4.y / npp, pz = p4.z / npp, pw = p4.w / npp;

    union { __bf16 h[4]; uint2 q; } cu, cp;
    cu.h[0] = (__bf16)ux; cu.h[1] = (__bf16)uy; cu.h[2] = (__bf16)uz; cu.h[3] = (__bf16)uw;
    cp.h[0] = (__bf16)px; cp.h[1] = (__bf16)py; cp.h[2] = (__bf16)pz; cp.h[3] = (__bf16)pw;
    ((uint2*)Uh)[r * 32 + l32] = cu.q;
    ((uint2*)Ph)[r * 32 + l32] = cp.q;

    const float dx = ux - px, dy = uy - py, dz = uz - pz, dw = uw - pw;
    float al = dx*dx + dy*dy + dz*dz + dw*dw;
    for (int off = 16; off; off >>= 1) al += __shfl_xor(al, off, 64);
    al += __shfl_xor(al, 32, 64);

    __shared__ float wsum[4];
    if (lane == 0) wsum[w] = al;
    __syncthreads();
    if (tid == 0)
        alignPart[blockIdx.x] = (double)wsum[0] + (double)wsum[1]
                              + (double)wsum[2] + (double)wsum[3];
}

// ---------------------------------------------------------------------------
// Kernel 2: 128x128 tile of G = Xn*Xn^T per block (bi<=bj, off-diag x2).
//   4 waves (2x2), wave tile 64x64 (acc[4][4]). Single 32KB LDS buffer:
//   A-half [128][64]bf16 at 0, B-half at 16384; K staged in two halves.
//   __launch_bounds__(256,4) caps VGPR<=128 -> 4 blocks/CU (16 waves/CU):
//   one block's exp epilogue overlaps other blocks' MFMA/staging.
//   Rows = 128B = 8 chunks of 16B; LDS(r,c) holds global chunk c^(r&7)
//   (pre-swizzled source, linear gload_lds dest; reads XOR back).
// ---------------------------------------------------------------------------
__global__ __launch_bounds__(256, 4) void gram_kernel(
    const __bf16* __restrict__ Uh, const __bf16* __restrict__ Ph,
    double* __restrict__ Spart)
{
    __shared__ __align__(16) unsigned char smem[32768];
    __shared__ float wsum[4];

    const int bid = blockIdx.x;
    const int mat = bid >= JOBS_PER_MAT;
    const int t   = bid - (mat ? JOBS_PER_MAT : 0);

    int bi = (int)((NB + 0.5f) - sqrtf((NB + 0.5f) * (NB + 0.5f) - 2.0f * (float)t));
    if (bi > 0 && tri(bi) > t) --bi;
    if (tri(bi + 1) <= t) ++bi;
    const int bj = bi + (t - tri(bi));

    const char* __restrict__ Xb = (const char*)(mat ? Ph : Uh);

    const int tid  = threadIdx.x;
    const int lane = tid & 63;
    const int w    = tid >> 6;

    // staging: thread covers global rows r0+8i, chunk (lane&7), pre-swizzled
    const int r0 = w * 32 + (lane >> 3);
    const int gcOff = (((lane & 7) ^ (r0 & 7)) << 4);
    const char* gA0 = Xb + (size_t)(bi * 128 + r0) * 256 + gcOff;
    const char* gB0 = Xb + (size_t)(bj * 128 + r0) * 256 + gcOff;
    unsigned char* lA0 = smem + w * 4096;     // wave-uniform LDS base (A)

#define STAGE(h)                                                           \
    {                                                                      \
        const int hb = (h) * 128;                                          \
        _Pragma("unroll")                                                  \
        for (int i_ = 0; i_ < 4; ++i_) {                                   \
            gload16(gA0 + hb + i_ * 2048, lA0 + i_ * 1024);                \
            gload16(gB0 + hb + i_ * 2048, lA0 + 16384 + i_ * 1024);        \
        }                                                                  \
    }

    // fragment read geometry (2x2 waves, each owns 64x64)
    const int wm = w >> 1, wn = w & 1;
    const int lr = lane & 15;
    const int lg = lane >> 4;
    const unsigned cxor = (unsigned)(lr & 7);
    const unsigned aOff = (unsigned)(wm * 64 + lr) * 128;
    const unsigned bOff = (unsigned)(wn * 64 + lr) * 128 + 16384;

    f32x4 acc[4][4];
#pragma unroll
    for (int mi = 0; mi < 4; ++mi)
#pragma unroll
        for (int ni = 0; ni < 4; ++ni)
            acc[mi][ni] = (f32x4){0.f, 0.f, 0.f, 0.f};

#define COMPUTE                                                             \
    {                                                                       \
        _Pragma("unroll")                                                   \
        for (int ks2 = 0; ks2 < 2; ++ks2) {                                 \
            const unsigned sc = (((unsigned)(ks2 * 4 + lg)) ^ cxor) << 4;   \
            bf16x8 a[4], b[4];                                              \
            _Pragma("unroll")                                               \
            for (int mi = 0; mi < 4; ++mi)                                  \
                a[mi] = *reinterpret_cast<const bf16x8*>(                   \
                    smem + aOff + mi * 2048 + sc);                          \
            _Pragma("unroll")                                               \
            for (int ni = 0; ni < 4; ++ni)                                  \
                b[ni] = *reinterpret_cast<const bf16x8*>(                   \
                    smem + bOff + ni * 2048 + sc);                          \
            _Pragma("unroll")                                               \
            for (int mi = 0; mi < 4; ++mi)                                  \
                _Pragma("unroll")                                           \
                for (int ni = 0; ni < 4; ++ni)                              \
                    acc[mi][ni] = __builtin_amdgcn_mfma_f32_16x16x32_bf16(  \
                        a[mi], b[ni], acc[mi][ni], 0, 0, 0);                \
        }                                                                   \
    }

    STAGE(0)
    __syncthreads();        // h0 staged
    COMPUTE
    __syncthreads();        // h0 reads done; buffer reusable
    STAGE(1)
    __syncthreads();        // h1 staged
    COMPUTE

    // epilogue: sum exp2(C1*dot - C1) == exp(-2*d^2); 1 fma + 1 exp + 1 add
    const float C1 = 4.0f * 1.4426950408889634f;   // 4*log2(e)
    float s0 = 0.f, s1 = 0.f, s2 = 0.f, s3 = 0.f;
#pragma unroll
    for (int mi = 0; mi < 4; ++mi)
#pragma unroll
        for (int ni = 0; ni < 4; ++ni) {
            const f32x4 v = acc[mi][ni];
            s0 += fast_exp2(v[0] * C1 - C1);
            s1 += fast_exp2(v[1] * C1 - C1);
            s2 += fast_exp2(v[2] * C1 - C1);
            s3 += fast_exp2(v[3] * C1 - C1);
        }

    const float s = waveReduceSum((s0 + s1) + (s2 + s3));
    if (lane == 0) wsum[w] = s;
    __syncthreads();
    if (tid == 0) {
        double bs = (double)wsum[0] + (double)wsum[1]
                  + (double)wsum[2] + (double)wsum[3];
        if (bi != bj) bs *= 2.0;     // off-diagonal tile counts twice in S_full
        Spart[bid] = bs;
    }
#undef STAGE
#undef COMPUTE
}

// ---------------------------------------------------------------------------
// Kernel 3: final reduction + loss formula. One block, 1024 threads.
// ---------------------------------------------------------------------------
__global__ __launch_bounds__(1024) void finalize_kernel(
    const double* __restrict__ alignPart, const double* __restrict__ Spart,
    float* __restrict__ out)
{
    const int tid = threadIdx.x;
    double a = 0.0, su = 0.0, sp = 0.0;
    for (int i = tid; i < 1024; i += 1024) a += alignPart[i];
    for (int i = tid; i < 2 * JOBS_PER_MAT; i += 1024) {
        const double v = Spart[i];
        if (i < JOBS_PER_MAT) su += v; else sp += v;
    }
    for (int off = 32; off; off >>= 1) {
        a  += __shfl_xor(a,  off, 64);
        su += __shfl_xor(su, off, 64);
        sp += __shfl_xor(sp, off, 64);
    }
    __shared__ double sh[3][16];
    const int lane = tid & 63, wid = tid >> 6;
    if (lane == 0) { sh[0][wid] = a; sh[1][wid] = su; sh[2][wid] = sp; }
    __syncthreads();
    if (tid == 0) {
        double A = 0.0, SU = 0.0, SP = 0.0;
        for (int i = 0; i < 16; ++i) { A += sh[0][i]; SU += sh[1][i]; SP += sh[2][i]; }
        const double Nd = 8192.0;
        const double npairs = Nd * (Nd - 1.0) * 0.5;
        const double align = A / Nd;
        const double mu = (SU - Nd) * 0.5 / npairs;
        const double mp = (SP - Nd) * 0.5 / npairs;
        const double uniform = 0.25 * (log(mu) + log(mp));
        out[0] = (float)((align + uniform) / 8192.0);
    }
}

// ---------------------------------------------------------------------------
extern "C" void kernel_launch(void* const* d_in, const int* in_sizes, int n_in,
                              void* d_out, int out_size, void* d_ws, size_t ws_size,
                              hipStream_t stream)
{
    const float* users = (const float*)d_in[0];
    const float* pos   = (const float*)d_in[1];
    // d_in[2] (neg_items) intentionally unused, matching the reference.
    float* out = (float*)d_out;

    char* ws = (char*)d_ws;
    __bf16* Uh = (__bf16*)ws;                              // 2 MiB
    __bf16* Ph = (__bf16*)(ws + 2097152);                  // 2 MiB
    double* alignPart = (double*)(ws + 4194304);           // 1024 doubles
    double* Spart     = (double*)(ws + 4194304 + 8192);    // 4160 doubles

    hipLaunchKernelGGL(prep_kernel, dim3(1024), dim3(256), 0, stream,
                       users, pos, Uh, Ph, alignPart);
    hipLaunchKernelGGL(gram_kernel, dim3(2 * JOBS_PER_MAT), dim3(256), 0, stream,
                       Uh, Ph, Spart);
    hipLaunchKernelGGL(finalize_kernel, dim3(1), dim3(1024), 0, stream,
                       alignPart, Spart, out);
}